// Round 11
// baseline (388.370 us; speedup 1.0000x reference)
//
#include <hip/hip_runtime.h>
#include <math.h>

#define NN 50000     // nodes
#define NE 650000    // edges (without self loops)
#define NET 700000   // NE + NN self loops
#define FD 256       // H*C = 4*64
#define NEG 0.2f

static __device__ __forceinline__ float lrelu(float v){ return v > 0.f ? v : NEG*v; }

// bf16 helpers
static __device__ __forceinline__ unsigned short f2bf(float f){
  union { float f; unsigned u; } v; v.f = f;
  unsigned r = v.u + 0x7fff + ((v.u >> 16) & 1);
  return (unsigned short)(r >> 16);
}
static __device__ __forceinline__ float bf2f(unsigned short h){
  union { unsigned u; float f; } v; v.u = ((unsigned)h) << 16;
  return v.f;
}
static __device__ __forceinline__ float bflo(unsigned u){ return __uint_as_float(u << 16); }
static __device__ __forceinline__ float bfhi(unsigned u){ return __uint_as_float(u & 0xffff0000u); }

// async global->LDS DMA, 16 B per lane, LDS dest = uniform base + lane*16 (m97/m104)
static __device__ __forceinline__ void gload_lds16(const unsigned short* g, unsigned short* l){
  __builtin_amdgcn_global_load_lds(
      (const __attribute__((address_space(1))) unsigned int*)(g),
      (__attribute__((address_space(3))) unsigned int*)(l), 16, 0, 0);
}

typedef __attribute__((ext_vector_type(8))) short short8_t;  // 8 bf16 = 4 VGPR
typedef __attribute__((ext_vector_type(4))) float f32x4;

// ---------------- fused init: cast x/W1/W2 + degree count (disjoint block ranges) ----
#define NX (NN*128)
#define CAST_ELEMS (NX + 128*256 + 256*256)
#define CAST_BLOCKS ((CAST_ELEMS/4 + 255)/256)
#define CNT_BLOCKS ((NET + 255)/256)
__global__ void init_fused(const float* __restrict__ x, const float* __restrict__ W1,
                           const float* __restrict__ W2,
                           unsigned short* __restrict__ xh, unsigned short* __restrict__ xl,
                           unsigned short* __restrict__ bt1h, unsigned short* __restrict__ bt1l,
                           unsigned short* __restrict__ bt2h, unsigned short* __restrict__ bt2l,
                           const int* __restrict__ ei, int* __restrict__ deg){
  int b = blockIdx.x;
  if (b >= CAST_BLOCKS){
    int e = (b - CAST_BLOCKS)*256 + threadIdx.x;
    if (e < NET){
      int d = (e < NE) ? ei[NE + e] : (e - NE);
      atomicAdd(&deg[d], 1);
    }
    return;
  }
  int i = (b*256 + threadIdx.x)*4;
  if (i < NX){
    float4 f = *(const float4*)(x + i);
    ushort4 h, l;
    h.x = f2bf(f.x); l.x = f2bf(f.x - bf2f(h.x));
    h.y = f2bf(f.y); l.y = f2bf(f.y - bf2f(h.y));
    h.z = f2bf(f.z); l.z = f2bf(f.z - bf2f(h.z));
    h.w = f2bf(f.w); l.w = f2bf(f.w - bf2f(h.w));
    *(ushort4*)(xh + i) = h;
    *(ushort4*)(xl + i) = l;
    return;
  }
  int e, K;
  const float* B;
  unsigned short *bh, *bl;
  if (i < NX + 128*256){ e = i - NX; K = 128; B = W1; bh = bt1h; bl = bt1l; }
  else if (i < CAST_ELEMS){ e = i - NX - 128*256; K = 256; B = W2; bh = bt2h; bl = bt2l; }
  else return;
  int k = e >> 8, n = e & 255;
  float4 f = *(const float4*)(B + e);
  #pragma unroll
  for (int j=0;j<4;j++){
    float fv = (j==0)?f.x:(j==1)?f.y:(j==2)?f.z:f.w;
    unsigned short h = f2bf(fv);
    bh[(n+j)*K + k] = h;
    bl[(n+j)*K + k] = f2bf(fv - bf2f(h));
  }
}

// ---------------- single-dispatch CSR scan: one block, shfl-based ----------------
// Replaces scan_block+scan_tops+scan_add (three dependent passes) with one
// kernel: 49 chunks of 1024, wave shfl scan + cross-wave LDS scan + carry.
__global__ __launch_bounds__(1024) void scan_all(const int* __restrict__ deg,
                                                 int* __restrict__ indptr,
                                                 int* __restrict__ cursor){
  __shared__ int wsum[16];
  __shared__ int carrysh;
  int t = threadIdx.x, w = t >> 6, lane = t & 63;
  if (t == 0) carrysh = 0;
  __syncthreads();
  for (int c = 0; c < (NN + 1023)/1024; ++c){
    int i = c*1024 + t;
    int v = (i < NN) ? deg[i] : 0;
    int s = v;                               // wave inclusive scan
    for (int off=1; off<64; off<<=1){
      int u = __shfl_up(s, off);
      if (lane >= off) s += u;
    }
    if (lane == 63) wsum[w] = s;
    __syncthreads();
    if (t < 16){                              // wave0 scans the 16 wave sums
      int xx = wsum[t];
      int e2 = xx;
      for (int off=1; off<16; off<<=1){
        int u = __shfl_up(e2, off);
        if (t >= off) e2 += u;
      }
      wsum[t] = e2 - xx;                      // exclusive
    }
    __syncthreads();
    int excl = s - v + wsum[w] + carrysh;
    if (i < NN){ indptr[i] = excl; cursor[i] = excl; }
    __syncthreads();
    if (t == 1023) carrysh = excl + v;        // chunk-inclusive running total
  }
  if (t == 0) indptr[NN] = NET;
}

__global__ void scatter_csr(const int* __restrict__ ei, int* __restrict__ cursor, int* __restrict__ csr){
  int e = blockIdx.x*blockDim.x + threadIdx.x;
  if (e >= NET) return;
  int s, d;
  if (e < NE){ s = ei[e]; d = ei[NE+e]; } else { s = e-NE; d = e-NE; }
  int pos = atomicAdd(&cursor[d], 1);
  csr[pos] = s;
}

// ---------------- split-bf16 MFMA GEMM: wave tile 64x128 (LDS-pressure cut) ----
// acc = Ah*Bh + Ah*Bl + Al*Bh (~fp32 precision). Block tile 128x128, BK=32,
// TWO waves of 64: wave w owns rows w*64..w*64+63, all 128 cols (mt=4, nt=8).
// MFMA:ds_read ratio 96:24 = 4:1 (was 3:1) -> 25% less LDS traffic per FLOP;
// the K-loop is LDS-issue-bound (m134: ds_read_b128 ~12cy), so this is the lever.
// Contiguous k-major LDS (64 B/row) per global_load_lds constraint (m104).
template<int K>
__global__ __launch_bounds__(128, 2) void gemm_mfma(const unsigned short* __restrict__ Ahg,
                                                    const unsigned short* __restrict__ Alg,
                                                    const unsigned short* __restrict__ Bth,
                                                    const unsigned short* __restrict__ Btl,
                                                    unsigned short* __restrict__ Cb,
                                                    const float* __restrict__ a_src,
                                                    const float* __restrict__ a_dst,
                                                    float* __restrict__ al,
                                                    int M){
  constexpr int ITERS = K/32;
  // one arena so wave scratch (16 KB) is guaranteed contiguous:
  // Ah = +0, Al = +4096, Bh = +8192, Bl = +12288 (shorts)
  __shared__ unsigned short smem[4*128*32];   // 32 KB
  unsigned short* Ah = smem;
  unsigned short* Al = smem + 4096;
  unsigned short* Bh = smem + 8192;
  unsigned short* Bl = smem + 12288;
  int t = threadIdx.x;
  int wave = t >> 6, lane = t & 63;
  int quad = lane >> 4, l16 = lane & 15;
  int bm0 = blockIdx.y*128, bn0 = blockIdx.x*128;

  // staging: wave0 -> Ah+Al (rows bm0..+127), wave1 -> Bh+Bl (rows bn0..+127)
  const unsigned short* g0 = wave ? Bth : Ahg;
  const unsigned short* g1 = wave ? Btl : Alg;
  unsigned short* l0 = wave ? Bh : Ah;
  unsigned short* l1 = wave ? Bl : Al;
  int sbase = wave ? bn0 : bm0;
  int srow = lane >> 2;
  int skg  = (lane & 3) * 8;
  int rr[8];
  #pragma unroll
  for (int i=0;i<8;i++){
    int r = sbase + i*16 + srow;
    if (!wave) r = min(r, M-1);      // clamp: dup rows, never OOB
    rr[i] = r;
  }
  const unsigned short* g0p = g0 + skg;
  const unsigned short* g1p = g1 + skg;

  f32x4 acc[4][8];
  #pragma unroll
  for (int i=0;i<4;i++)
    #pragma unroll
    for (int j=0;j<8;j++) acc[i][j] = (f32x4){0.f,0.f,0.f,0.f};

  // prologue: DMA iter 0
  #pragma unroll
  for (int i=0;i<8;i++){
    gload_lds16(g0p + (size_t)rr[i]*K, l0 + i*512);
    gload_lds16(g1p + (size_t)rr[i]*K, l1 + i*512);
  }

  #pragma unroll
  for (int it=0; it<ITERS; ++it){
    __syncthreads();                 // drain DMA(it)

    // B frags upfront (shared cols, both waves read all 8)
    short8_t bfh[8], bfl[8];
    #pragma unroll
    for (int nt=0; nt<8; ++nt){
      int col = nt*16 + l16;
      bfh[nt] = *(short8_t*)&Bh[col*32 + quad*8];
      bfl[nt] = *(short8_t*)&Bl[col*32 + quad*8];
    }
    // A frags streamed per-mt (keeps VGPRs ~215, no spill)
    #pragma unroll
    for (int mt=0; mt<4; ++mt){
      int row = wave*64 + mt*16 + l16;
      short8_t ah = *(short8_t*)&Ah[row*32 + quad*8];
      short8_t alw = *(short8_t*)&Al[row*32 + quad*8];
      #pragma unroll
      for (int nt=0; nt<8; ++nt){
        acc[mt][nt] = __builtin_amdgcn_mfma_f32_16x16x32_bf16(ah,  bfh[nt], acc[mt][nt], 0,0,0);
        acc[mt][nt] = __builtin_amdgcn_mfma_f32_16x16x32_bf16(ah,  bfl[nt], acc[mt][nt], 0,0,0);
        acc[mt][nt] = __builtin_amdgcn_mfma_f32_16x16x32_bf16(alw, bfh[nt], acc[mt][nt], 0,0,0);
      }
    }
    __syncthreads();                 // all frag reads done; LDS writable

    if (it+1 < ITERS){
      int k0 = (it+1)*32;
      #pragma unroll
      for (int i=0;i<8;i++){
        gload_lds16(g0p + (size_t)rr[i]*K + k0, l0 + i*512);
        gload_lds16(g1p + (size_t)rr[i]*K + k0, l1 + i*512);
      }
    }
  }
  // After the last in-loop barrier all frag reads completed; each wave now uses
  // its own contiguous 16 KB (smem + wave*8192 shorts) as private scratch.
  unsigned short* scratch = smem + wave*8192;

  // ---- epilogue 1: fused al via LDS transpose; 2 head-halves x 2 passes ----
  // wave covers rows bm0+wave*64..+63, cols bn0..bn0+127 (heads (bn0>>6)+{0,1})
  int grow = bm0 + wave*64 + lane;
  #pragma unroll
  for (int h=0; h<2; ++h){
    int head_w = (bn0 >> 6) + h;
    float cs[4], cd[4];
    #pragma unroll
    for (int n4=0; n4<4; ++n4){
      cs[n4] = a_src[head_w*64 + n4*16 + l16];
      cd[n4] = a_dst[head_w*64 + n4*16 + l16];
    }
    float* fsc = (float*)scratch;    // 64 x 17 floats = 4352 B
    #pragma unroll
    for (int pass=0; pass<2; ++pass){
      #pragma unroll
      for (int mt=0; mt<4; ++mt)
        #pragma unroll
        for (int r=0; r<4; ++r){
          float p = 0.f;
          #pragma unroll
          for (int n4=0; n4<4; ++n4)
            p += acc[mt][h*4+n4][r] * (pass ? cd[n4] : cs[n4]);
          fsc[(mt*16 + quad*4 + r)*17 + l16] = p;
        }
      float s = 0.f;
      #pragma unroll
      for (int j=0; j<16; ++j) s += fsc[lane*17 + j];
      if (grow < M) al[grow*8 + pass*4 + head_w] = s;
    }
  }

  // ---- epilogue 2: Cb bf16 via wave-private LDS tile (64x128) + dwordx4 ----
  unsigned short* tile = scratch;    // 16 KB
  #pragma unroll
  for (int mt=0; mt<4; ++mt)
    #pragma unroll
    for (int r=0; r<4; ++r){
      int rl = mt*16 + quad*4 + r;
      #pragma unroll
      for (int nt=0; nt<8; ++nt)
        tile[rl*128 + nt*16 + l16] = f2bf(acc[mt][nt][r]);
    }
  int orow = lane >> 4, ocol = (lane & 15) * 8;   // 4 rows x 256 B per instr
  #pragma unroll
  for (int it2=0; it2<16; ++it2){
    int rl = it2*4 + orow;
    int row = bm0 + wave*64 + rl;
    if (row < M){
      uint4 v = *(uint4*)&tile[rl*128 + ocol];
      *(uint4*)(Cb + (size_t)row*FD + bn0 + ocol) = v;
    }
  }
}

// ---------------- GAT aggregation: one node per 32-lane half, 8-deep gather MLP ----
template<bool FUSE_W3>
__global__ __launch_bounds__(256) void gat_agg(const unsigned short* __restrict__ hb,
                                               const float* __restrict__ al,
                                               const int* __restrict__ indptr, const int* __restrict__ csr,
                                               const float* __restrict__ bias,
                                               unsigned short* __restrict__ outh,
                                               unsigned short* __restrict__ outl,
                                               const float* __restrict__ W3,
                                               float* __restrict__ h3){
  __shared__ float ebuf[8][128];   // per node: 32 slots x 4 heads
  __shared__ int   sbuf[8][32];    // per node: 32 byte-offsets
  int wave = threadIdx.x >> 6, lane = threadIdx.x & 63;
  int half = lane >> 5, l32 = lane & 31;
  int slot = wave*2 + half;
  int n = blockIdx.x*8 + slot;
  if (n >= NN) return;
  int head8 = l32 >> 3;
  int2 ip = *(const int2*)(indptr + n);
  int base = ip.x, deg = ip.y - ip.x;
  float4 ald = *(const float4*)(al + n*8 + 4);
  float* eb = &ebuf[slot][0];
  int*   sb = &sbuf[slot][0];
  const char* hp = (const char*)hb + l32*16;

  float acc[8] = {0.f,0.f,0.f,0.f,0.f,0.f,0.f,0.f};
  float4 esum = make_float4(0.f,0.f,0.f,0.f);

  for (int j0 = 0; j0 < deg; j0 += 32){
    int j = j0 + l32;
    float4 e4 = make_float4(0.f,0.f,0.f,0.f);
    int sj = 0;
    if (j < deg){
      sj = csr[base + j];
      float4 als = *(const float4*)(al + sj*8);
      e4.x = __expf(lrelu(als.x + ald.x));
      e4.y = __expf(lrelu(als.y + ald.y));
      e4.z = __expf(lrelu(als.z + ald.z));
      e4.w = __expf(lrelu(als.w + ald.w));
      esum.x += e4.x; esum.y += e4.y; esum.z += e4.z; esum.w += e4.w;
    }
    *(float4*)&eb[l32*4] = e4;
    sb[l32] = sj << 9;                       // byte offset (FD*2 = 512)
    int cnt  = min(32, deg - j0);
    int cpad = (cnt + 7) & ~7;               // pad reads row 0 with alpha 0
    for (int tt = 0; tt < cpad; tt += 8){
      uint4 r[8];
      float v[8];
      #pragma unroll
      for (int q=0; q<8; ++q){
        int o = sb[tt+q];
        v[q] = eb[(tt+q)*4 + head8];
        r[q] = *(const uint4*)(hp + o);
      }
      #pragma unroll
      for (int q=0; q<8; ++q){
        acc[0]+=v[q]*bflo(r[q].x); acc[1]+=v[q]*bfhi(r[q].x);
        acc[2]+=v[q]*bflo(r[q].y); acc[3]+=v[q]*bfhi(r[q].y);
        acc[4]+=v[q]*bflo(r[q].z); acc[5]+=v[q]*bfhi(r[q].z);
        acc[6]+=v[q]*bflo(r[q].w); acc[7]+=v[q]*bfhi(r[q].w);
      }
    }
  }

  for (int off=16; off; off>>=1){
    esum.x += __shfl_xor(esum.x, off);
    esum.y += __shfl_xor(esum.y, off);
    esum.z += __shfl_xor(esum.z, off);
    esum.w += __shfl_xor(esum.w, off);
  }
  float sH = (head8==0)?esum.x:(head8==1)?esum.y:(head8==2)?esum.z:esum.w;
  float inv = 1.f/(sH + 1e-16f);
  int ch0 = l32*8;
  float4 b0 = *(const float4*)(bias + ch0);
  float4 b1 = *(const float4*)(bias + ch0 + 4);
  float o[8];
  o[0]=acc[0]*inv+b0.x; o[1]=acc[1]*inv+b0.y; o[2]=acc[2]*inv+b0.z; o[3]=acc[3]*inv+b0.w;
  o[4]=acc[4]*inv+b1.x; o[5]=acc[5]*inv+b1.y; o[6]=acc[6]*inv+b1.z; o[7]=acc[7]*inv+b1.w;
  #pragma unroll
  for (int i=0;i<8;i++) o[i] = o[i] > 0.f ? o[i] : expm1f(o[i]);   // elu

  if (FUSE_W3){
    float4 w0 = *(const float4*)(W3 + ch0);
    float4 w1 = *(const float4*)(W3 + ch0 + 4);
    float p = o[0]*w0.x + o[1]*w0.y + o[2]*w0.z + o[3]*w0.w
            + o[4]*w1.x + o[5]*w1.y + o[6]*w1.z + o[7]*w1.w;
    #pragma unroll
    for (int off=16; off; off>>=1) p += __shfl_xor(p, off);
    if (l32 == 0) h3[n] = p;
  } else {
    unsigned hi[4], lo[4];
    #pragma unroll
    for (int i=0;i<4;i++){
      unsigned short h0 = f2bf(o[2*i]),   h1 = f2bf(o[2*i+1]);
      unsigned short g0 = f2bf(o[2*i]   - bf2f(h0));
      unsigned short g1 = f2bf(o[2*i+1] - bf2f(h1));
      hi[i] = (unsigned)h0 | ((unsigned)h1 << 16);
      lo[i] = (unsigned)g0 | ((unsigned)g1 << 16);
    }
    *(uint4*)(outh + (size_t)n*FD + ch0) = make_uint4(hi[0],hi[1],hi[2],hi[3]);
    *(uint4*)(outl + (size_t)n*FD + ch0) = make_uint4(lo[0],lo[1],lo[2],lo[3]);
  }
}

// ---------------- layer 3: scalar GAT on h3, 4 lanes/node, single pass ----------
__global__ __launch_bounds__(256) void gat_agg3(const float* __restrict__ h3, const int* __restrict__ indptr,
                                                const int* __restrict__ csr, const float* __restrict__ asrc,
                                                const float* __restrict__ adst, const float* __restrict__ b3,
                                                float* __restrict__ out){
  int tid = blockIdx.x*blockDim.x + threadIdx.x;
  int n = tid >> 2, sub = tid & 3;
  if (n >= NN) return;
  float as = asrc[0], ad = adst[0];
  float hd = h3[n]*ad;
  int2 ip = *(const int2*)(indptr + n);
  float s = 0.f, w = 0.f;
  for (int e = ip.x + sub; e < ip.y; e += 4){
    float hv = h3[csr[e]];
    float ee = __expf(lrelu(as*hv + hd));
    s += ee; w += ee*hv;
  }
  s += __shfl_xor(s, 1); w += __shfl_xor(w, 1);
  s += __shfl_xor(s, 2); w += __shfl_xor(w, 2);
  if (sub == 0) out[n] = w/(s + 1e-16f) + b3[0];
}

extern "C" void kernel_launch(void* const* d_in, const int* in_sizes, int n_in,
                              void* d_out, int out_size, void* d_ws, size_t ws_size,
                              hipStream_t stream){
  const float* x   = (const float*)d_in[0];
  const int*   ei  = (const int*)d_in[1];
  const float* W1  = (const float*)d_in[2];
  const float* as1 = (const float*)d_in[3];
  const float* ad1 = (const float*)d_in[4];
  const float* b1  = (const float*)d_in[5];
  const float* W2  = (const float*)d_in[6];
  const float* as2 = (const float*)d_in[7];
  const float* ad2 = (const float*)d_in[8];
  const float* b2  = (const float*)d_in[9];
  const float* W3  = (const float*)d_in[10];
  const float* as3 = (const float*)d_in[11];
  const float* ad3 = (const float*)d_in[12];
  const float* b3  = (const float*)d_in[13];
  float* outp = (float*)d_out;

  char* w = (char*)d_ws;
  size_t off = 0;
  auto alloc = [&](size_t bytes)->void*{
    void* p = w + off; off += (bytes + 255) & ~(size_t)255; return p;
  };
  unsigned short* hb  = (unsigned short*)alloc((size_t)NN*FD*2);  // 25.6 MB (Cb)
  unsigned short* oh  = (unsigned short*)alloc((size_t)NN*FD*2);  // 25.6 MB
  unsigned short* ol  = (unsigned short*)alloc((size_t)NN*FD*2);  // 25.6 MB
  unsigned short* xh  = (unsigned short*)alloc((size_t)NN*128*2); // 12.8 MB
  unsigned short* xl  = (unsigned short*)alloc((size_t)NN*128*2); // 12.8 MB
  float* al    = (float*)alloc((size_t)NN*8*4);                   // 1.6 MB
  int*   indptr= (int*)alloc((size_t)(NN+1)*4);
  int*   cursor= (int*)alloc((size_t)NN*4);
  int*   csr   = (int*)alloc((size_t)NET*4);                      // 2.8 MB
  float* h3    = (float*)alloc((size_t)NN*4);
  unsigned short* bt1h = (unsigned short*)alloc((size_t)256*128*2);
  unsigned short* bt1l = (unsigned short*)alloc((size_t)256*128*2);
  unsigned short* bt2h = (unsigned short*)alloc((size_t)256*256*2);
  unsigned short* bt2l = (unsigned short*)alloc((size_t)256*256*2);

  // ---- CSR build + casts (fused; graph identical for all layers) ----
  hipMemsetAsync(cursor, 0, (size_t)NN*4, stream);
  init_fused<<<CAST_BLOCKS + CNT_BLOCKS, 256, 0, stream>>>(x, W1, W2, xh, xl,
                                                           bt1h, bt1l, bt2h, bt2l,
                                                           ei, cursor);
  scan_all<<<1, 1024, 0, stream>>>(cursor, indptr, cursor);
  scatter_csr<<<(NET+255)/256, 256, 0, stream>>>(ei, cursor, csr);

  dim3 gemm_grid(FD/128, (NN+127)/128);
  int agg_blocks = (NN+7)/8;

  // ---- layer 1 ----
  gemm_mfma<128><<<gemm_grid, 128, 0, stream>>>(xh, xl, bt1h, bt1l, hb, as1, ad1, al, NN);
  gat_agg<false><<<agg_blocks, 256, 0, stream>>>(hb, al, indptr, csr, b1, oh, ol, nullptr, nullptr);
  // ---- layer 2 (fused W3 gemv; no oh/ol write) ----
  gemm_mfma<256><<<gemm_grid, 128, 0, stream>>>(oh, ol, bt2h, bt2l, hb, as2, ad2, al, NN);
  gat_agg<true><<<agg_blocks, 256, 0, stream>>>(hb, al, indptr, csr, b2, nullptr, nullptr, W3, h3);
  // ---- layer 3 ----
  gat_agg3<<<(NN*4+255)/256, 256, 0, stream>>>(h3, indptr, csr, as3, ad3, b3, outp);
}

// Round 12
// 387.105 us; speedup vs baseline: 1.0033x; 1.0033x over previous
//
#include <hip/hip_runtime.h>
#include <math.h>

#define NN 50000     // nodes
#define NE 650000    // edges (without self loops)
#define NET 700000   // NE + NN self loops
#define FD 256       // H*C = 4*64
#define NEG 0.2f

static __device__ __forceinline__ float lrelu(float v){ return v > 0.f ? v : NEG*v; }

// bf16 helpers
static __device__ __forceinline__ unsigned short f2bf(float f){
  union { float f; unsigned u; } v; v.f = f;
  unsigned r = v.u + 0x7fff + ((v.u >> 16) & 1);
  return (unsigned short)(r >> 16);
}
static __device__ __forceinline__ float bf2f(unsigned short h){
  union { unsigned u; float f; } v; v.u = ((unsigned)h) << 16;
  return v.f;
}
static __device__ __forceinline__ float bflo(unsigned u){ return __uint_as_float(u << 16); }
static __device__ __forceinline__ float bfhi(unsigned u){ return __uint_as_float(u & 0xffff0000u); }

// async global->LDS DMA, 16 B per lane, LDS dest = uniform base + lane*16 (m97/m104)
static __device__ __forceinline__ void gload_lds16(const unsigned short* g, unsigned short* l){
  __builtin_amdgcn_global_load_lds(
      (const __attribute__((address_space(1))) unsigned int*)(g),
      (__attribute__((address_space(3))) unsigned int*)(l), 16, 0, 0);
}

typedef __attribute__((ext_vector_type(8))) short short8_t;  // 8 bf16 = 4 VGPR
typedef __attribute__((ext_vector_type(4))) float f32x4;

// ---------------- fused init: cast x/W1/W2 + degree count (disjoint block ranges) ----
#define NX (NN*128)
#define CAST_ELEMS (NX + 128*256 + 256*256)
#define CAST_BLOCKS ((CAST_ELEMS/4 + 255)/256)
#define CNT_BLOCKS ((NET + 255)/256)
__global__ void init_fused(const float* __restrict__ x, const float* __restrict__ W1,
                           const float* __restrict__ W2,
                           unsigned short* __restrict__ xh, unsigned short* __restrict__ xl,
                           unsigned short* __restrict__ bt1h, unsigned short* __restrict__ bt1l,
                           unsigned short* __restrict__ bt2h, unsigned short* __restrict__ bt2l,
                           const int* __restrict__ ei, int* __restrict__ deg){
  int b = blockIdx.x;
  if (b >= CAST_BLOCKS){
    int e = (b - CAST_BLOCKS)*256 + threadIdx.x;
    if (e < NET){
      int d = (e < NE) ? ei[NE + e] : (e - NE);
      atomicAdd(&deg[d], 1);
    }
    return;
  }
  int i = (b*256 + threadIdx.x)*4;
  if (i < NX){
    float4 f = *(const float4*)(x + i);
    ushort4 h, l;
    h.x = f2bf(f.x); l.x = f2bf(f.x - bf2f(h.x));
    h.y = f2bf(f.y); l.y = f2bf(f.y - bf2f(h.y));
    h.z = f2bf(f.z); l.z = f2bf(f.z - bf2f(h.z));
    h.w = f2bf(f.w); l.w = f2bf(f.w - bf2f(h.w));
    *(ushort4*)(xh + i) = h;
    *(ushort4*)(xl + i) = l;
    return;
  }
  int e, K;
  const float* B;
  unsigned short *bh, *bl;
  if (i < NX + 128*256){ e = i - NX; K = 128; B = W1; bh = bt1h; bl = bt1l; }
  else if (i < CAST_ELEMS){ e = i - NX - 128*256; K = 256; B = W2; bh = bt2h; bl = bt2l; }
  else return;
  int k = e >> 8, n = e & 255;
  float4 f = *(const float4*)(B + e);
  #pragma unroll
  for (int j=0;j<4;j++){
    float fv = (j==0)?f.x:(j==1)?f.y:(j==2)?f.z:f.w;
    unsigned short h = f2bf(fv);
    bh[(n+j)*K + k] = h;
    bl[(n+j)*K + k] = f2bf(fv - bf2f(h));
  }
}

// ---------------- single-dispatch CSR scan: one block, shfl-based ----------------
__global__ __launch_bounds__(1024) void scan_all(const int* __restrict__ deg,
                                                 int* __restrict__ indptr,
                                                 int* __restrict__ cursor){
  __shared__ int wsum[16];
  __shared__ int carrysh;
  int t = threadIdx.x, w = t >> 6, lane = t & 63;
  if (t == 0) carrysh = 0;
  __syncthreads();
  for (int c = 0; c < (NN + 1023)/1024; ++c){
    int i = c*1024 + t;
    int v = (i < NN) ? deg[i] : 0;
    int s = v;                               // wave inclusive scan
    for (int off=1; off<64; off<<=1){
      int u = __shfl_up(s, off);
      if (lane >= off) s += u;
    }
    if (lane == 63) wsum[w] = s;
    __syncthreads();
    if (t < 16){                              // wave0 scans the 16 wave sums
      int xx = wsum[t];
      int e2 = xx;
      for (int off=1; off<16; off<<=1){
        int u = __shfl_up(e2, off);
        if (t >= off) e2 += u;
      }
      wsum[t] = e2 - xx;                      // exclusive
    }
    __syncthreads();
    int excl = s - v + wsum[w] + carrysh;
    if (i < NN){ indptr[i] = excl; cursor[i] = excl; }
    __syncthreads();
    if (t == 1023) carrysh = excl + v;        // chunk-inclusive running total
  }
  if (t == 0) indptr[NN] = NET;
}

__global__ void scatter_csr(const int* __restrict__ ei, int* __restrict__ cursor, int* __restrict__ csr){
  int e = blockIdx.x*blockDim.x + threadIdx.x;
  if (e >= NET) return;
  int s, d;
  if (e < NE){ s = ei[e]; d = ei[NE+e]; } else { s = e-NE; d = e-NE; }
  int pos = atomicAdd(&cursor[d], 1);
  csr[pos] = s;
}

// ---------------- split-bf16 MFMA GEMM (R10-proven config), pipelined DMA ----
// acc = Ah*Bh + Ah*Bl + Al*Bh (~fp32 precision). Tile 128x128, BK=32, 4 waves
// of 64, wave tile 64x64 (3:1 MFMA:ds_read). R11 lesson: 64x128 wave tile
// (4:1) regresses — acc+Bfrag VGPR blows past the 128-reg occupancy step.
// Contiguous k-major LDS (64 B/row) per global_load_lds constraint (m104).
// K-loop pipelined: frag ds_reads -> barrier -> DMA(next) -> MFMA(cur).
template<int K>
__global__ __launch_bounds__(256, 3) void gemm_mfma(const unsigned short* __restrict__ Ahg,
                                                    const unsigned short* __restrict__ Alg,
                                                    const unsigned short* __restrict__ Bth,
                                                    const unsigned short* __restrict__ Btl,
                                                    unsigned short* __restrict__ Cb,
                                                    const float* __restrict__ a_src,
                                                    const float* __restrict__ a_dst,
                                                    float* __restrict__ al,
                                                    int M){
  constexpr int ITERS = K/32;
  __shared__ unsigned short Ah[128*32], Al[128*32], Bh[128*32], Bl[128*32]; // 8 KB each
  int t = threadIdx.x;
  int wave = t >> 6, lane = t & 63;
  int wm = wave >> 1, wn = wave & 1;
  int quad = lane >> 4, l16 = lane & 15;
  int bm0 = blockIdx.y*128, bn0 = blockIdx.x*128;

  const unsigned short* gsrc = (wave==0)?Ahg:(wave==1)?Alg:(wave==2)?Bth:Btl;
  unsigned short* lbuf       = (wave==0)?Ah :(wave==1)?Al :(wave==2)?Bh :Bl;
  int sbase = (wave < 2) ? bm0 : bn0;
  int srow = lane >> 2;
  int skg  = (lane & 3) * 8;

  // per-row global base pointers (row index constant across k-iters)
  const unsigned short* gp[8];
  #pragma unroll
  for (int i=0;i<8;i++){
    int r = sbase + i*16 + srow;
    if (wave < 2) r = min(r, M-1);   // clamp: dup rows, never OOB
    gp[i] = gsrc + (size_t)r*K + skg;
  }

  f32x4 acc[4][4];
  #pragma unroll
  for (int i=0;i<4;i++)
    #pragma unroll
    for (int j=0;j<4;j++) acc[i][j] = (f32x4){0.f,0.f,0.f,0.f};

  // prologue: DMA iter 0
  #pragma unroll
  for (int i=0;i<8;i++) gload_lds16(gp[i], lbuf + i*512);

  #pragma unroll
  for (int it=0; it<ITERS; ++it){
    __syncthreads();                       // drain DMA(it)

    short8_t afh[4], afl[4], bfh[4], bfl[4];
    #pragma unroll
    for (int mt=0; mt<4; ++mt){
      int row = wm*64 + mt*16 + l16;
      afh[mt] = *(short8_t*)&Ah[row*32 + quad*8];
      afl[mt] = *(short8_t*)&Al[row*32 + quad*8];
    }
    #pragma unroll
    for (int nt=0; nt<4; ++nt){
      int col = wn*64 + nt*16 + l16;
      bfh[nt] = *(short8_t*)&Bh[col*32 + quad*8];
      bfl[nt] = *(short8_t*)&Bl[col*32 + quad*8];
    }
    __syncthreads();                       // all frag reads done; LDS writable

    if (it+1 < ITERS){
      int k0 = (it+1)*32;
      #pragma unroll
      for (int i=0;i<8;i++) gload_lds16(gp[i] + k0, lbuf + i*512);
    }

    #pragma unroll
    for (int mt=0; mt<4; ++mt)
      #pragma unroll
      for (int nt=0; nt<4; ++nt){
        acc[mt][nt] = __builtin_amdgcn_mfma_f32_16x16x32_bf16(afh[mt], bfh[nt], acc[mt][nt], 0,0,0);
        acc[mt][nt] = __builtin_amdgcn_mfma_f32_16x16x32_bf16(afh[mt], bfl[nt], acc[mt][nt], 0,0,0);
        acc[mt][nt] = __builtin_amdgcn_mfma_f32_16x16x32_bf16(afl[mt], bfh[nt], acc[mt][nt], 0,0,0);
      }
  }
  // frag reads all completed before the last in-loop barrier; LDS now
  // wave-private scratch (each wave only touches its own lbuf below).

  // ---- epilogue 1: fused al via LDS transpose (stride 17 floats) ----
  int head_w = (bn0 >> 6) + wn;
  float cs[4], cd[4];
  #pragma unroll
  for (int nt=0; nt<4; ++nt){
    cs[nt] = a_src[head_w*64 + nt*16 + l16];
    cd[nt] = a_dst[head_w*64 + nt*16 + l16];
  }
  {
    float* fsc = (float*)lbuf;
    int grow = bm0 + wm*64 + lane;
    #pragma unroll
    for (int pass=0; pass<2; ++pass){
      #pragma unroll
      for (int mt=0; mt<4; ++mt)
        #pragma unroll
        for (int r=0; r<4; ++r){
          float p = 0.f;
          #pragma unroll
          for (int nt=0; nt<4; ++nt)
            p += acc[mt][nt][r] * (pass ? cd[nt] : cs[nt]);
          fsc[(mt*16 + quad*4 + r)*17 + l16] = p;
        }
      float s = 0.f;
      #pragma unroll
      for (int j=0; j<16; ++j) s += fsc[lane*17 + j];
      if (grow < M) al[grow*8 + pass*4 + head_w] = s;
    }
  }

  // ---- epilogue 2: Cb bf16 via per-wave LDS tile + coalesced dwordx4 ----
  unsigned short* tile = lbuf;
  #pragma unroll
  for (int mt=0; mt<4; ++mt)
    #pragma unroll
    for (int r=0; r<4; ++r){
      int rl = mt*16 + quad*4 + r;
      #pragma unroll
      for (int nt=0; nt<4; ++nt)
        tile[rl*64 + nt*16 + l16] = f2bf(acc[mt][nt][r]);
    }
  int orow = lane >> 3, ocol = (lane & 7) * 8;
  #pragma unroll
  for (int it=0; it<8; ++it){
    int rl = it*8 + orow;
    int row = bm0 + wm*64 + rl;
    if (row < M){
      uint4 v = *(uint4*)&tile[rl*64 + ocol];
      *(uint4*)(Cb + (size_t)row*FD + bn0 + wn*64 + ocol) = v;
    }
  }
}

// ---------------- GAT aggregation: one node per 32-lane half, 8-deep gather MLP ----
template<bool FUSE_W3>
__global__ __launch_bounds__(256) void gat_agg(const unsigned short* __restrict__ hb,
                                               const float* __restrict__ al,
                                               const int* __restrict__ indptr, const int* __restrict__ csr,
                                               const float* __restrict__ bias,
                                               unsigned short* __restrict__ outh,
                                               unsigned short* __restrict__ outl,
                                               const float* __restrict__ W3,
                                               float* __restrict__ h3){
  __shared__ float ebuf[8][128];   // per node: 32 slots x 4 heads
  __shared__ int   sbuf[8][32];    // per node: 32 byte-offsets
  int wave = threadIdx.x >> 6, lane = threadIdx.x & 63;
  int half = lane >> 5, l32 = lane & 31;
  int slot = wave*2 + half;
  int n = blockIdx.x*8 + slot;
  if (n >= NN) return;
  int head8 = l32 >> 3;
  int2 ip = *(const int2*)(indptr + n);
  int base = ip.x, deg = ip.y - ip.x;
  float4 ald = *(const float4*)(al + n*8 + 4);
  float* eb = &ebuf[slot][0];
  int*   sb = &sbuf[slot][0];
  const char* hp = (const char*)hb + l32*16;

  float acc[8] = {0.f,0.f,0.f,0.f,0.f,0.f,0.f,0.f};
  float4 esum = make_float4(0.f,0.f,0.f,0.f);

  for (int j0 = 0; j0 < deg; j0 += 32){
    int j = j0 + l32;
    float4 e4 = make_float4(0.f,0.f,0.f,0.f);
    int sj = 0;
    if (j < deg){
      sj = csr[base + j];
      float4 als = *(const float4*)(al + sj*8);
      e4.x = __expf(lrelu(als.x + ald.x));
      e4.y = __expf(lrelu(als.y + ald.y));
      e4.z = __expf(lrelu(als.z + ald.z));
      e4.w = __expf(lrelu(als.w + ald.w));
      esum.x += e4.x; esum.y += e4.y; esum.z += e4.z; esum.w += e4.w;
    }
    *(float4*)&eb[l32*4] = e4;
    sb[l32] = sj << 9;                       // byte offset (FD*2 = 512)
    int cnt  = min(32, deg - j0);
    int cpad = (cnt + 7) & ~7;               // pad reads row 0 with alpha 0
    for (int tt = 0; tt < cpad; tt += 8){
      uint4 r[8];
      float v[8];
      #pragma unroll
      for (int q=0; q<8; ++q){
        int o = sb[tt+q];
        v[q] = eb[(tt+q)*4 + head8];
        r[q] = *(const uint4*)(hp + o);
      }
      #pragma unroll
      for (int q=0; q<8; ++q){
        acc[0]+=v[q]*bflo(r[q].x); acc[1]+=v[q]*bfhi(r[q].x);
        acc[2]+=v[q]*bflo(r[q].y); acc[3]+=v[q]*bfhi(r[q].y);
        acc[4]+=v[q]*bflo(r[q].z); acc[5]+=v[q]*bfhi(r[q].z);
        acc[6]+=v[q]*bflo(r[q].w); acc[7]+=v[q]*bfhi(r[q].w);
      }
    }
  }

  for (int off=16; off; off>>=1){
    esum.x += __shfl_xor(esum.x, off);
    esum.y += __shfl_xor(esum.y, off);
    esum.z += __shfl_xor(esum.z, off);
    esum.w += __shfl_xor(esum.w, off);
  }
  float sH = (head8==0)?esum.x:(head8==1)?esum.y:(head8==2)?esum.z:esum.w;
  float inv = 1.f/(sH + 1e-16f);
  int ch0 = l32*8;
  float4 b0 = *(const float4*)(bias + ch0);
  float4 b1 = *(const float4*)(bias + ch0 + 4);
  float o[8];
  o[0]=acc[0]*inv+b0.x; o[1]=acc[1]*inv+b0.y; o[2]=acc[2]*inv+b0.z; o[3]=acc[3]*inv+b0.w;
  o[4]=acc[4]*inv+b1.x; o[5]=acc[5]*inv+b1.y; o[6]=acc[6]*inv+b1.z; o[7]=acc[7]*inv+b1.w;
  #pragma unroll
  for (int i=0;i<8;i++) o[i] = o[i] > 0.f ? o[i] : expm1f(o[i]);   // elu

  if (FUSE_W3){
    float4 w0 = *(const float4*)(W3 + ch0);
    float4 w1 = *(const float4*)(W3 + ch0 + 4);
    float p = o[0]*w0.x + o[1]*w0.y + o[2]*w0.z + o[3]*w0.w
            + o[4]*w1.x + o[5]*w1.y + o[6]*w1.z + o[7]*w1.w;
    #pragma unroll
    for (int off=16; off; off>>=1) p += __shfl_xor(p, off);
    if (l32 == 0) h3[n] = p;
  } else {
    unsigned hi[4], lo[4];
    #pragma unroll
    for (int i=0;i<4;i++){
      unsigned short h0 = f2bf(o[2*i]),   h1 = f2bf(o[2*i+1]);
      unsigned short g0 = f2bf(o[2*i]   - bf2f(h0));
      unsigned short g1 = f2bf(o[2*i+1] - bf2f(h1));
      hi[i] = (unsigned)h0 | ((unsigned)h1 << 16);
      lo[i] = (unsigned)g0 | ((unsigned)g1 << 16);
    }
    *(uint4*)(outh + (size_t)n*FD + ch0) = make_uint4(hi[0],hi[1],hi[2],hi[3]);
    *(uint4*)(outl + (size_t)n*FD + ch0) = make_uint4(lo[0],lo[1],lo[2],lo[3]);
  }
}

// ---------------- layer 3: scalar GAT on h3, 4 lanes/node, single pass ----------
__global__ __launch_bounds__(256) void gat_agg3(const float* __restrict__ h3, const int* __restrict__ indptr,
                                                const int* __restrict__ csr, const float* __restrict__ asrc,
                                                const float* __restrict__ adst, const float* __restrict__ b3,
                                                float* __restrict__ out){
  int tid = blockIdx.x*blockDim.x + threadIdx.x;
  int n = tid >> 2, sub = tid & 3;
  if (n >= NN) return;
  float as = asrc[0], ad = adst[0];
  float hd = h3[n]*ad;
  int2 ip = *(const int2*)(indptr + n);
  float s = 0.f, w = 0.f;
  for (int e = ip.x + sub; e < ip.y; e += 4){
    float hv = h3[csr[e]];
    float ee = __expf(lrelu(as*hv + hd));
    s += ee; w += ee*hv;
  }
  s += __shfl_xor(s, 1); w += __shfl_xor(w, 1);
  s += __shfl_xor(s, 2); w += __shfl_xor(w, 2);
  if (sub == 0) out[n] = w/(s + 1e-16f) + b3[0];
}

extern "C" void kernel_launch(void* const* d_in, const int* in_sizes, int n_in,
                              void* d_out, int out_size, void* d_ws, size_t ws_size,
                              hipStream_t stream){
  const float* x   = (const float*)d_in[0];
  const int*   ei  = (const int*)d_in[1];
  const float* W1  = (const float*)d_in[2];
  const float* as1 = (const float*)d_in[3];
  const float* ad1 = (const float*)d_in[4];
  const float* b1  = (const float*)d_in[5];
  const float* W2  = (const float*)d_in[6];
  const float* as2 = (const float*)d_in[7];
  const float* ad2 = (const float*)d_in[8];
  const float* b2  = (const float*)d_in[9];
  const float* W3  = (const float*)d_in[10];
  const float* as3 = (const float*)d_in[11];
  const float* ad3 = (const float*)d_in[12];
  const float* b3  = (const float*)d_in[13];
  float* outp = (float*)d_out;

  char* w = (char*)d_ws;
  size_t off = 0;
  auto alloc = [&](size_t bytes)->void*{
    void* p = w + off; off += (bytes + 255) & ~(size_t)255; return p;
  };
  unsigned short* hb  = (unsigned short*)alloc((size_t)NN*FD*2);  // 25.6 MB (Cb)
  unsigned short* oh  = (unsigned short*)alloc((size_t)NN*FD*2);  // 25.6 MB
  unsigned short* ol  = (unsigned short*)alloc((size_t)NN*FD*2);  // 25.6 MB
  unsigned short* xh  = (unsigned short*)alloc((size_t)NN*128*2); // 12.8 MB
  unsigned short* xl  = (unsigned short*)alloc((size_t)NN*128*2); // 12.8 MB
  float* al    = (float*)alloc((size_t)NN*8*4);                   // 1.6 MB
  int*   indptr= (int*)alloc((size_t)(NN+1)*4);
  int*   cursor= (int*)alloc((size_t)NN*4);
  int*   csr   = (int*)alloc((size_t)NET*4);                      // 2.8 MB
  float* h3    = (float*)alloc((size_t)NN*4);
  unsigned short* bt1h = (unsigned short*)alloc((size_t)256*128*2);
  unsigned short* bt1l = (unsigned short*)alloc((size_t)256*128*2);
  unsigned short* bt2h = (unsigned short*)alloc((size_t)256*256*2);
  unsigned short* bt2l = (unsigned short*)alloc((size_t)256*256*2);

  // ---- CSR build + casts (fused; graph identical for all layers) ----
  hipMemsetAsync(cursor, 0, (size_t)NN*4, stream);
  init_fused<<<CAST_BLOCKS + CNT_BLOCKS, 256, 0, stream>>>(x, W1, W2, xh, xl,
                                                           bt1h, bt1l, bt2h, bt2l,
                                                           ei, cursor);
  scan_all<<<1, 1024, 0, stream>>>(cursor, indptr, cursor);
  scatter_csr<<<(NET+255)/256, 256, 0, stream>>>(ei, cursor, csr);

  dim3 gemm_grid(FD/128, (NN+127)/128);
  int agg_blocks = (NN+7)/8;

  // ---- layer 1 ----
  gemm_mfma<128><<<gemm_grid, 256, 0, stream>>>(xh, xl, bt1h, bt1l, hb, as1, ad1, al, NN);
  gat_agg<false><<<agg_blocks, 256, 0, stream>>>(hb, al, indptr, csr, b1, oh, ol, nullptr, nullptr);
  // ---- layer 2 (fused W3 gemv; no oh/ol write) ----
  gemm_mfma<256><<<gemm_grid, 256, 0, stream>>>(oh, ol, bt2h, bt2l, hb, as2, ad2, al, NN);
  gat_agg<true><<<agg_blocks, 256, 0, stream>>>(hb, al, indptr, csr, b2, nullptr, nullptr, W3, h3);
  // ---- layer 3 ----
  gat_agg3<<<(NN*4+255)/256, 256, 0, stream>>>(h3, indptr, csr, as3, ad3, b3, outp);
}

// Round 13
// 342.221 us; speedup vs baseline: 1.1349x; 1.1312x over previous
//
#include <hip/hip_runtime.h>
#include <math.h>

#define NN 50000     // nodes
#define NE 650000    // edges (without self loops)
#define NET 700000   // NE + NN self loops
#define FD 256       // H*C = 4*64
#define NEG 0.2f
#define NB 49        // scan blocks = ceil(NN/1024)

static __device__ __forceinline__ float lrelu(float v){ return v > 0.f ? v : NEG*v; }

// bf16 helpers
static __device__ __forceinline__ unsigned short f2bf(float f){
  union { float f; unsigned u; } v; v.f = f;
  unsigned r = v.u + 0x7fff + ((v.u >> 16) & 1);
  return (unsigned short)(r >> 16);
}
static __device__ __forceinline__ float bf2f(unsigned short h){
  union { unsigned u; float f; } v; v.u = ((unsigned)h) << 16;
  return v.f;
}
static __device__ __forceinline__ float bflo(unsigned u){ return __uint_as_float(u << 16); }
static __device__ __forceinline__ float bfhi(unsigned u){ return __uint_as_float(u & 0xffff0000u); }

// async global->LDS DMA, 16 B per lane, LDS dest = uniform base + lane*16 (m97/m104)
static __device__ __forceinline__ void gload_lds16(const unsigned short* g, unsigned short* l){
  __builtin_amdgcn_global_load_lds(
      (const __attribute__((address_space(1))) unsigned int*)(g),
      (__attribute__((address_space(3))) unsigned int*)(l), 16, 0, 0);
}

typedef __attribute__((ext_vector_type(8))) short short8_t;  // 8 bf16 = 4 VGPR
typedef __attribute__((ext_vector_type(4))) float f32x4;

// ---------------- fused init: cast x/W1/W2 + degree count (disjoint block ranges) ----
#define NX (NN*128)
#define CAST_ELEMS (NX + 128*256 + 256*256)
#define CAST_BLOCKS ((CAST_ELEMS/4 + 255)/256)
#define CNT_BLOCKS ((NET + 255)/256)
__global__ void init_fused(const float* __restrict__ x, const float* __restrict__ W1,
                           const float* __restrict__ W2,
                           unsigned short* __restrict__ xh, unsigned short* __restrict__ xl,
                           unsigned short* __restrict__ bt1h, unsigned short* __restrict__ bt1l,
                           unsigned short* __restrict__ bt2h, unsigned short* __restrict__ bt2l,
                           const int* __restrict__ ei, int* __restrict__ deg){
  int b = blockIdx.x;
  if (b >= CAST_BLOCKS){
    int e = (b - CAST_BLOCKS)*256 + threadIdx.x;
    if (e < NET){
      int d = (e < NE) ? ei[NE + e] : (e - NE);
      atomicAdd(&deg[d], 1);
    }
    return;
  }
  int i = (b*256 + threadIdx.x)*4;
  if (i < NX){
    float4 f = *(const float4*)(x + i);
    ushort4 h, l;
    h.x = f2bf(f.x); l.x = f2bf(f.x - bf2f(h.x));
    h.y = f2bf(f.y); l.y = f2bf(f.y - bf2f(h.y));
    h.z = f2bf(f.z); l.z = f2bf(f.z - bf2f(h.z));
    h.w = f2bf(f.w); l.w = f2bf(f.w - bf2f(h.w));
    *(ushort4*)(xh + i) = h;
    *(ushort4*)(xl + i) = l;
    return;
  }
  int e, K;
  const float* B;
  unsigned short *bh, *bl;
  if (i < NX + 128*256){ e = i - NX; K = 128; B = W1; bh = bt1h; bl = bt1l; }
  else if (i < CAST_ELEMS){ e = i - NX - 128*256; K = 256; B = W2; bh = bt2h; bl = bt2l; }
  else return;
  int k = e >> 8, n = e & 255;
  float4 f = *(const float4*)(B + e);
  #pragma unroll
  for (int j=0;j<4;j++){
    float fv = (j==0)?f.x:(j==1)?f.y:(j==2)?f.z:f.w;
    unsigned short h = f2bf(fv);
    bh[(n+j)*K + k] = h;
    bl[(n+j)*K + k] = f2bf(fv - bf2f(h));
  }
}

// ---------------- CSR scan (parallel: 49 blocks, then 196 blocks) ----------------
// R12 lesson: the single-block fused scan_all serialized 49 dependent
// global-latency iterations on one CU (~45us) — parallel 2-dispatch scan wins.
__global__ void scan_block(const int* __restrict__ deg, int* __restrict__ excl, int* __restrict__ bsums){
  __shared__ int sh[256];
  int t = threadIdx.x;
  int i0 = blockIdx.x*1024 + t*4;
  int v0 = (i0+0 < NN) ? deg[i0+0] : 0;
  int v1 = (i0+1 < NN) ? deg[i0+1] : 0;
  int v2 = (i0+2 < NN) ? deg[i0+2] : 0;
  int v3 = (i0+3 < NN) ? deg[i0+3] : 0;
  int tot = v0+v1+v2+v3;
  sh[t] = tot;
  __syncthreads();
  for (int off=1; off<256; off<<=1){
    int x = (t>=off) ? sh[t-off] : 0;
    __syncthreads();
    sh[t] += x;
    __syncthreads();
  }
  int base = sh[t] - tot;
  if (i0+0 < NN) excl[i0+0] = base;
  if (i0+1 < NN) excl[i0+1] = base + v0;
  if (i0+2 < NN) excl[i0+2] = base + v0+v1;
  if (i0+3 < NN) excl[i0+3] = base + v0+v1+v2;
  if (t == 255) bsums[blockIdx.x] = sh[255];
}

// scan_add with inlined block-sum scan (wave 0 redundantly scans the NB sums)
__global__ void scan_add(int* __restrict__ indptr, const int* __restrict__ bsums, int* __restrict__ cursor){
  __shared__ int boff[64];
  if (threadIdx.x < 64){
    int lane = threadIdx.x;
    int v = (lane < NB) ? bsums[lane] : 0;
    int orig = v;
    for (int off=1; off<64; off<<=1){
      int u = __shfl_up(v, off);
      if (lane >= off) v += u;
    }
    boff[lane] = v - orig;   // exclusive
  }
  __syncthreads();
  int i = blockIdx.x*blockDim.x + threadIdx.x;
  if (i < NN){
    int v = indptr[i] + boff[i>>10];
    indptr[i] = v;
    cursor[i] = v;
  }
  if (i == 0) indptr[NN] = NET;
}

__global__ void scatter_csr(const int* __restrict__ ei, int* __restrict__ cursor, int* __restrict__ csr){
  int e = blockIdx.x*blockDim.x + threadIdx.x;
  if (e >= NET) return;
  int s, d;
  if (e < NE){ s = ei[e]; d = ei[NE+e]; } else { s = e-NE; d = e-NE; }
  int pos = atomicAdd(&cursor[d], 1);
  csr[pos] = s;
}

// ---------------- split-bf16 MFMA GEMM (R10-proven config), pipelined DMA ----
// acc = Ah*Bh + Ah*Bl + Al*Bh (~fp32 precision). Tile 128x128, BK=32, 4 waves
// of 64, wave tile 64x64 (3:1 MFMA:ds_read). R11 lesson: 64x128 wave tile
// regressed on VGPR/occupancy. Contiguous k-major LDS (64 B/row) per
// global_load_lds constraint (m104). K-loop pipelined: frag ds_reads ->
// barrier -> DMA(next) -> MFMA(cur).
template<int K>
__global__ __launch_bounds__(256, 3) void gemm_mfma(const unsigned short* __restrict__ Ahg,
                                                    const unsigned short* __restrict__ Alg,
                                                    const unsigned short* __restrict__ Bth,
                                                    const unsigned short* __restrict__ Btl,
                                                    unsigned short* __restrict__ Cb,
                                                    const float* __restrict__ a_src,
                                                    const float* __restrict__ a_dst,
                                                    float* __restrict__ al,
                                                    int M){
  constexpr int ITERS = K/32;
  __shared__ unsigned short Ah[128*32], Al[128*32], Bh[128*32], Bl[128*32]; // 8 KB each
  int t = threadIdx.x;
  int wave = t >> 6, lane = t & 63;
  int wm = wave >> 1, wn = wave & 1;
  int quad = lane >> 4, l16 = lane & 15;
  int bm0 = blockIdx.y*128, bn0 = blockIdx.x*128;

  const unsigned short* gsrc = (wave==0)?Ahg:(wave==1)?Alg:(wave==2)?Bth:Btl;
  unsigned short* lbuf       = (wave==0)?Ah :(wave==1)?Al :(wave==2)?Bh :Bl;
  int sbase = (wave < 2) ? bm0 : bn0;
  int srow = lane >> 2;
  int skg  = (lane & 3) * 8;

  // per-row global base pointers (row index constant across k-iters)
  const unsigned short* gp[8];
  #pragma unroll
  for (int i=0;i<8;i++){
    int r = sbase + i*16 + srow;
    if (wave < 2) r = min(r, M-1);   // clamp: dup rows, never OOB
    gp[i] = gsrc + (size_t)r*K + skg;
  }

  f32x4 acc[4][4];
  #pragma unroll
  for (int i=0;i<4;i++)
    #pragma unroll
    for (int j=0;j<4;j++) acc[i][j] = (f32x4){0.f,0.f,0.f,0.f};

  // prologue: DMA iter 0
  #pragma unroll
  for (int i=0;i<8;i++) gload_lds16(gp[i], lbuf + i*512);

  #pragma unroll
  for (int it=0; it<ITERS; ++it){
    __syncthreads();                       // drain DMA(it)

    short8_t afh[4], afl[4], bfh[4], bfl[4];
    #pragma unroll
    for (int mt=0; mt<4; ++mt){
      int row = wm*64 + mt*16 + l16;
      afh[mt] = *(short8_t*)&Ah[row*32 + quad*8];
      afl[mt] = *(short8_t*)&Al[row*32 + quad*8];
    }
    #pragma unroll
    for (int nt=0; nt<4; ++nt){
      int col = wn*64 + nt*16 + l16;
      bfh[nt] = *(short8_t*)&Bh[col*32 + quad*8];
      bfl[nt] = *(short8_t*)&Bl[col*32 + quad*8];
    }
    __syncthreads();                       // all frag reads done; LDS writable

    if (it+1 < ITERS){
      int k0 = (it+1)*32;
      #pragma unroll
      for (int i=0;i<8;i++) gload_lds16(gp[i] + k0, lbuf + i*512);
    }

    #pragma unroll
    for (int mt=0; mt<4; ++mt)
      #pragma unroll
      for (int nt=0; nt<4; ++nt){
        acc[mt][nt] = __builtin_amdgcn_mfma_f32_16x16x32_bf16(afh[mt], bfh[nt], acc[mt][nt], 0,0,0);
        acc[mt][nt] = __builtin_amdgcn_mfma_f32_16x16x32_bf16(afh[mt], bfl[nt], acc[mt][nt], 0,0,0);
        acc[mt][nt] = __builtin_amdgcn_mfma_f32_16x16x32_bf16(afl[mt], bfh[nt], acc[mt][nt], 0,0,0);
      }
  }
  // frag reads all completed before the last in-loop barrier; LDS now
  // wave-private scratch (each wave only touches its own lbuf below).

  // ---- epilogue 1: fused al via LDS transpose (stride 17 floats) ----
  int head_w = (bn0 >> 6) + wn;
  float cs[4], cd[4];
  #pragma unroll
  for (int nt=0; nt<4; ++nt){
    cs[nt] = a_src[head_w*64 + nt*16 + l16];
    cd[nt] = a_dst[head_w*64 + nt*16 + l16];
  }
  {
    float* fsc = (float*)lbuf;
    int grow = bm0 + wm*64 + lane;
    #pragma unroll
    for (int pass=0; pass<2; ++pass){
      #pragma unroll
      for (int mt=0; mt<4; ++mt)
        #pragma unroll
        for (int r=0; r<4; ++r){
          float p = 0.f;
          #pragma unroll
          for (int nt=0; nt<4; ++nt)
            p += acc[mt][nt][r] * (pass ? cd[nt] : cs[nt]);
          fsc[(mt*16 + quad*4 + r)*17 + l16] = p;
        }
      float s = 0.f;
      #pragma unroll
      for (int j=0; j<16; ++j) s += fsc[lane*17 + j];
      if (grow < M) al[grow*8 + pass*4 + head_w] = s;
    }
  }

  // ---- epilogue 2: Cb bf16 via per-wave LDS tile + coalesced dwordx4 ----
  unsigned short* tile = lbuf;
  #pragma unroll
  for (int mt=0; mt<4; ++mt)
    #pragma unroll
    for (int r=0; r<4; ++r){
      int rl = mt*16 + quad*4 + r;
      #pragma unroll
      for (int nt=0; nt<4; ++nt)
        tile[rl*64 + nt*16 + l16] = f2bf(acc[mt][nt][r]);
    }
  int orow = lane >> 3, ocol = (lane & 7) * 8;
  #pragma unroll
  for (int it=0; it<8; ++it){
    int rl = it*8 + orow;
    int row = bm0 + wm*64 + rl;
    if (row < M){
      uint4 v = *(uint4*)&tile[rl*64 + ocol];
      *(uint4*)(Cb + (size_t)row*FD + bn0 + wn*64 + ocol) = v;
    }
  }
}

// ---------------- GAT aggregation: one node per 32-lane half, 8-deep gather MLP ----
template<bool FUSE_W3>
__global__ __launch_bounds__(256) void gat_agg(const unsigned short* __restrict__ hb,
                                               const float* __restrict__ al,
                                               const int* __restrict__ indptr, const int* __restrict__ csr,
                                               const float* __restrict__ bias,
                                               unsigned short* __restrict__ outh,
                                               unsigned short* __restrict__ outl,
                                               const float* __restrict__ W3,
                                               float* __restrict__ h3){
  __shared__ float ebuf[8][128];   // per node: 32 slots x 4 heads
  __shared__ int   sbuf[8][32];    // per node: 32 byte-offsets
  int wave = threadIdx.x >> 6, lane = threadIdx.x & 63;
  int half = lane >> 5, l32 = lane & 31;
  int slot = wave*2 + half;
  int n = blockIdx.x*8 + slot;
  if (n >= NN) return;
  int head8 = l32 >> 3;
  int2 ip = *(const int2*)(indptr + n);
  int base = ip.x, deg = ip.y - ip.x;
  float4 ald = *(const float4*)(al + n*8 + 4);
  float* eb = &ebuf[slot][0];
  int*   sb = &sbuf[slot][0];
  const char* hp = (const char*)hb + l32*16;

  float acc[8] = {0.f,0.f,0.f,0.f,0.f,0.f,0.f,0.f};
  float4 esum = make_float4(0.f,0.f,0.f,0.f);

  for (int j0 = 0; j0 < deg; j0 += 32){
    int j = j0 + l32;
    float4 e4 = make_float4(0.f,0.f,0.f,0.f);
    int sj = 0;
    if (j < deg){
      sj = csr[base + j];
      float4 als = *(const float4*)(al + sj*8);
      e4.x = __expf(lrelu(als.x + ald.x));
      e4.y = __expf(lrelu(als.y + ald.y));
      e4.z = __expf(lrelu(als.z + ald.z));
      e4.w = __expf(lrelu(als.w + ald.w));
      esum.x += e4.x; esum.y += e4.y; esum.z += e4.z; esum.w += e4.w;
    }
    *(float4*)&eb[l32*4] = e4;
    sb[l32] = sj << 9;                       // byte offset (FD*2 = 512)
    int cnt  = min(32, deg - j0);
    int cpad = (cnt + 7) & ~7;               // pad reads row 0 with alpha 0
    for (int tt = 0; tt < cpad; tt += 8){
      uint4 r[8];
      float v[8];
      #pragma unroll
      for (int q=0; q<8; ++q){
        int o = sb[tt+q];
        v[q] = eb[(tt+q)*4 + head8];
        r[q] = *(const uint4*)(hp + o);
      }
      #pragma unroll
      for (int q=0; q<8; ++q){
        acc[0]+=v[q]*bflo(r[q].x); acc[1]+=v[q]*bfhi(r[q].x);
        acc[2]+=v[q]*bflo(r[q].y); acc[3]+=v[q]*bfhi(r[q].y);
        acc[4]+=v[q]*bflo(r[q].z); acc[5]+=v[q]*bfhi(r[q].z);
        acc[6]+=v[q]*bflo(r[q].w); acc[7]+=v[q]*bfhi(r[q].w);
      }
    }
  }

  for (int off=16; off; off>>=1){
    esum.x += __shfl_xor(esum.x, off);
    esum.y += __shfl_xor(esum.y, off);
    esum.z += __shfl_xor(esum.z, off);
    esum.w += __shfl_xor(esum.w, off);
  }
  float sH = (head8==0)?esum.x:(head8==1)?esum.y:(head8==2)?esum.z:esum.w;
  float inv = 1.f/(sH + 1e-16f);
  int ch0 = l32*8;
  float4 b0 = *(const float4*)(bias + ch0);
  float4 b1 = *(const float4*)(bias + ch0 + 4);
  float o[8];
  o[0]=acc[0]*inv+b0.x; o[1]=acc[1]*inv+b0.y; o[2]=acc[2]*inv+b0.z; o[3]=acc[3]*inv+b0.w;
  o[4]=acc[4]*inv+b1.x; o[5]=acc[5]*inv+b1.y; o[6]=acc[6]*inv+b1.z; o[7]=acc[7]*inv+b1.w;
  #pragma unroll
  for (int i=0;i<8;i++) o[i] = o[i] > 0.f ? o[i] : expm1f(o[i]);   // elu

  if (FUSE_W3){
    float4 w0 = *(const float4*)(W3 + ch0);
    float4 w1 = *(const float4*)(W3 + ch0 + 4);
    float p = o[0]*w0.x + o[1]*w0.y + o[2]*w0.z + o[3]*w0.w
            + o[4]*w1.x + o[5]*w1.y + o[6]*w1.z + o[7]*w1.w;
    #pragma unroll
    for (int off=16; off; off>>=1) p += __shfl_xor(p, off);
    if (l32 == 0) h3[n] = p;
  } else {
    unsigned hi[4], lo[4];
    #pragma unroll
    for (int i=0;i<4;i++){
      unsigned short h0 = f2bf(o[2*i]),   h1 = f2bf(o[2*i+1]);
      unsigned short g0 = f2bf(o[2*i]   - bf2f(h0));
      unsigned short g1 = f2bf(o[2*i+1] - bf2f(h1));
      hi[i] = (unsigned)h0 | ((unsigned)h1 << 16);
      lo[i] = (unsigned)g0 | ((unsigned)g1 << 16);
    }
    *(uint4*)(outh + (size_t)n*FD + ch0) = make_uint4(hi[0],hi[1],hi[2],hi[3]);
    *(uint4*)(outl + (size_t)n*FD + ch0) = make_uint4(lo[0],lo[1],lo[2],lo[3]);
  }
}

// ---------------- layer 3: scalar GAT on h3, 4 lanes/node, single pass ----------
__global__ __launch_bounds__(256) void gat_agg3(const float* __restrict__ h3, const int* __restrict__ indptr,
                                                const int* __restrict__ csr, const float* __restrict__ asrc,
                                                const float* __restrict__ adst, const float* __restrict__ b3,
                                                float* __restrict__ out){
  int tid = blockIdx.x*blockDim.x + threadIdx.x;
  int n = tid >> 2, sub = tid & 3;
  if (n >= NN) return;
  float as = asrc[0], ad = adst[0];
  float hd = h3[n]*ad;
  int2 ip = *(const int2*)(indptr + n);
  float s = 0.f, w = 0.f;
  for (int e = ip.x + sub; e < ip.y; e += 4){
    float hv = h3[csr[e]];
    float ee = __expf(lrelu(as*hv + hd));
    s += ee; w += ee*hv;
  }
  s += __shfl_xor(s, 1); w += __shfl_xor(w, 1);
  s += __shfl_xor(s, 2); w += __shfl_xor(w, 2);
  if (sub == 0) out[n] = w/(s + 1e-16f) + b3[0];
}

extern "C" void kernel_launch(void* const* d_in, const int* in_sizes, int n_in,
                              void* d_out, int out_size, void* d_ws, size_t ws_size,
                              hipStream_t stream){
  const float* x   = (const float*)d_in[0];
  const int*   ei  = (const int*)d_in[1];
  const float* W1  = (const float*)d_in[2];
  const float* as1 = (const float*)d_in[3];
  const float* ad1 = (const float*)d_in[4];
  const float* b1  = (const float*)d_in[5];
  const float* W2  = (const float*)d_in[6];
  const float* as2 = (const float*)d_in[7];
  const float* ad2 = (const float*)d_in[8];
  const float* b2  = (const float*)d_in[9];
  const float* W3  = (const float*)d_in[10];
  const float* as3 = (const float*)d_in[11];
  const float* ad3 = (const float*)d_in[12];
  const float* b3  = (const float*)d_in[13];
  float* outp = (float*)d_out;

  char* w = (char*)d_ws;
  size_t off = 0;
  auto alloc = [&](size_t bytes)->void*{
    void* p = w + off; off += (bytes + 255) & ~(size_t)255; return p;
  };
  unsigned short* hb  = (unsigned short*)alloc((size_t)NN*FD*2);  // 25.6 MB (Cb)
  unsigned short* oh  = (unsigned short*)alloc((size_t)NN*FD*2);  // 25.6 MB
  unsigned short* ol  = (unsigned short*)alloc((size_t)NN*FD*2);  // 25.6 MB
  unsigned short* xh  = (unsigned short*)alloc((size_t)NN*128*2); // 12.8 MB
  unsigned short* xl  = (unsigned short*)alloc((size_t)NN*128*2); // 12.8 MB
  float* al    = (float*)alloc((size_t)NN*8*4);                   // 1.6 MB
  int*   indptr= (int*)alloc((size_t)(NN+1)*4);
  int*   cursor= (int*)alloc((size_t)NN*4);
  int*   csr   = (int*)alloc((size_t)NET*4);                      // 2.8 MB
  int*   bsums = (int*)alloc(64*4);
  float* h3    = (float*)alloc((size_t)NN*4);
  unsigned short* bt1h = (unsigned short*)alloc((size_t)256*128*2);
  unsigned short* bt1l = (unsigned short*)alloc((size_t)256*128*2);
  unsigned short* bt2h = (unsigned short*)alloc((size_t)256*256*2);
  unsigned short* bt2l = (unsigned short*)alloc((size_t)256*256*2);

  // ---- CSR build + casts (fused init; parallel 2-dispatch scan) ----
  hipMemsetAsync(cursor, 0, (size_t)NN*4, stream);
  init_fused<<<CAST_BLOCKS + CNT_BLOCKS, 256, 0, stream>>>(x, W1, W2, xh, xl,
                                                           bt1h, bt1l, bt2h, bt2l,
                                                           ei, cursor);
  scan_block<<<NB, 256, 0, stream>>>(cursor, indptr, bsums);
  scan_add<<<(NN+255)/256, 256, 0, stream>>>(indptr, bsums, cursor);
  scatter_csr<<<(NET+255)/256, 256, 0, stream>>>(ei, cursor, csr);

  dim3 gemm_grid(FD/128, (NN+127)/128);
  int agg_blocks = (NN+7)/8;

  // ---- layer 1 ----
  gemm_mfma<128><<<gemm_grid, 256, 0, stream>>>(xh, xl, bt1h, bt1l, hb, as1, ad1, al, NN);
  gat_agg<false><<<agg_blocks, 256, 0, stream>>>(hb, al, indptr, csr, b1, oh, ol, nullptr, nullptr);
  // ---- layer 2 (fused W3 gemv; no oh/ol write) ----
  gemm_mfma<256><<<gemm_grid, 256, 0, stream>>>(oh, ol, bt2h, bt2l, hb, as2, ad2, al, NN);
  gat_agg<true><<<agg_blocks, 256, 0, stream>>>(hb, al, indptr, csr, b2, nullptr, nullptr, W3, h3);
  // ---- layer 3 ----
  gat_agg3<<<(NN*4+255)/256, 256, 0, stream>>>(h3, indptr, csr, as3, ad3, b3, outp);
}